// Round 11
// baseline (23.348 us; speedup 1.0000x reference)
//
#include <hip/hip_runtime.h>
#include <stdint.h>

// Problem constants (match reference)
constexpr int NB = 256;      // batch
constexpr int NS = 64;       // sequence
constexpr int NIB = 32;      // bits per token
constexpr int NH = 4;        // heads
constexpr int SIMB = 12;     // sim address bits
constexpr int VALB = 10;     // val address bits
constexpr int OUTB = 12;     // out address bits

// Single-dispatch, no table packing, no conn staging, no stage-2 LDS pass.
// One block per batch b; 1024 threads = 16 waves; lane = j.
// vs round-10 proven ram_direct:
//  - ip/jp computed per-lane in registers (s = lane), stage 4 uses __shfl
//    broadcast instead of s_ip/s_jp LDS (+1 barrier removed)
//  - conn tables read directly from global (wave-uniform -> scalar loads)
// Stage 3/5/6 bodies byte-identical to round 10.
__global__ __launch_bounds__(1024) void ram_v2(
    const int* __restrict__ tokens,      // [B][S][IB]
    const int* __restrict__ sim_conn,    // [H][12]
    const float* __restrict__ sim_mem,   // [H][4096]
    const int* __restrict__ val_conn,    // [H][IB][10]
    const float* __restrict__ val_mem,   // [H][IB][1024]
    const float* __restrict__ agg_mem,   // [H][IB][65]
    const int* __restrict__ out_conn,    // [IB][12]
    const float* __restrict__ out_mem,   // [IB][4096]
    float* __restrict__ out)             // [B][S][IB]
{
    const int b = blockIdx.x;
    const int tid = threadIdx.x, lane = tid & 63, wave = tid >> 6;

    __shared__ uint32_t s_tok[NS];
    __shared__ uint64_t s_att[NS][NH];
    __shared__ uint64_t s_proj[NH][NIB];
    __shared__ uint32_t s_comb[NS][NH];

    // ---- stage 0: in-block token pack via ballot (proven) ----
    {
        const int base = b * (NS * NIB);
#pragma unroll
        for (int r = 0; r < 2; ++r) {
            const int e = r * 1024 + tid;              // covers 0..2047
            uint64_t m = __ballot(tokens[base + e] & 1);
            if (lane == 0) {
                int w = e >> 5;                        // even word index
                s_tok[w]     = (uint32_t)m;
                s_tok[w + 1] = (uint32_t)(m >> 32);
            }
        }
    }
    __syncthreads();

    // per-lane 38-bit val_in vector: bit c == val_in[j=lane][c]
    const uint32_t tkj = s_tok[lane];
    const uint32_t rev6 = __brev((uint32_t)lane) >> 26;
    const uint64_t V = (uint64_t)tkj | ((uint64_t)rev6 << 32);

    // ---- stage 2 (in-register, per lane, s = lane): sim addr i/j parts.
    //      sim_conn reads are wave-uniform -> scalar loads. ----
    uint32_t ipl[NH], jpl[NH];
#pragma unroll
    for (int h = 0; h < NH; ++h) {
        uint32_t ip = 0, jp = 0;
#pragma unroll
        for (int t = 0; t < SIMB; ++t) {
            int c = sim_conn[h * SIMB + t];
            uint32_t w = 1u << (SIMB - 1 - t);
            if (c < 32)      ip += ((tkj >> c) & 1u) * w;                     // qb
            else if (c < 64) jp += ((tkj >> (c - 32)) & 1u) * w;              // kb
            else if (c < 70) ip += (((uint32_t)lane >> (69 - c)) & 1u) * w;   // qp
            else             jp += (((uint32_t)lane >> (75 - c)) & 1u) * w;   // kp
        }
        ipl[h] = ip;
        jpl[h] = jp;
    }

    // ---- stage 3: proj masks via ballot. 16 waves x 8 = 128 (h,n).
    //      conn wave-uniform scalar loads; val read direct as float. ----
#pragma unroll
    for (int r = 0; r < 8; ++r) {
        const int hn = wave * 8 + r;
        const int* conn = val_conn + hn * VALB;
        uint32_t addr = 0;
#pragma unroll
        for (int t = 0; t < VALB; ++t)
            addr += (uint32_t)((V >> conn[t]) & 1ull) << (VALB - 1 - t);
        uint64_t m = __ballot(val_mem[hn * 1024 + addr] > 0.5f);
        if (lane == 0) s_proj[hn >> 5][hn & 31] = m;
    }

    // ---- stage 4: attend masks via ballot. 16 waves x 16 = 256 (i,h).
    //      i = wave*4 + (r>>2); h = (wave*16+r)&3 = r&3 (compile-time).
    //      ip[i][h] fetched via __shfl broadcast — no LDS, no extra barrier. ----
#pragma unroll
    for (int r = 0; r < 16; ++r) {
        const int h = r & 3;
        const int i = wave * 4 + (r >> 2);
        uint32_t ipv = (uint32_t)__shfl((int)ipl[h], i);
        uint32_t addr = ipv + jpl[h];
        uint64_t m = __ballot(sim_mem[h * 4096 + addr] > 0.5f);
        if (lane == 0) s_att[i][h] = m & (~0ull >> (63 - i));   // causal
    }
    __syncthreads();   // covers stage 3 + stage 4 writes

    // ---- stage 5: counts -> agg bit -> comb word. 1024 threads = (i,h,q).
    //      agg read direct as float (33 KB, L1-hot). ----
    {
        const int i = tid >> 4, h = (tid >> 2) & 3, q = tid & 3;
        const uint64_t am = s_att[i][h];
        uint32_t word = 0;
#pragma unroll
        for (int nn = 0; nn < 8; ++nn) {
            const int n = q * 8 + nn;
            int cnt = __popcll(am & s_proj[h][n]);     // exact integer in [0,64]
            uint32_t bit = (agg_mem[(h * NIB + n) * (NS + 1) + cnt] > 0.5f) ? 1u : 0u;
            word |= bit << n;
        }
        word = (am != 0ull) ? word : 0u;     // n_att > 0.5 gate (quad-uniform)
        word |= __shfl_xor(word, 1);
        word |= __shfl_xor(word, 2);
        if (q == 0) s_comb[i][h] = word;
    }
    __syncthreads();

    // ---- stage 6: out address gather + final float lookup. 2 outs/thread.
    //      out_conn read direct (384 ints, L1-hot). ----
    {
        const int n = tid & 31;
        const int ii = tid >> 5;                 // 0..31
        int conn[OUTB];
#pragma unroll
        for (int t = 0; t < OUTB; ++t) conn[t] = out_conn[n * OUTB + t];
        const float* om = out_mem + n * 4096;
#pragma unroll
        for (int k = 0; k < 2; ++k) {
            const int i = ii + k * 32;
            uint64_t lo = (uint64_t)s_comb[i][0] | ((uint64_t)s_comb[i][1] << 32);
            uint64_t hi = (uint64_t)s_comb[i][2] | ((uint64_t)s_comb[i][3] << 32);
            uint32_t addr = 0;
#pragma unroll
            for (int t = 0; t < OUTB; ++t) {
                int c = conn[t];
                uint64_t w = (c < 64) ? lo : hi;
                addr += (uint32_t)((w >> (c & 63)) & 1ull) << (OUTB - 1 - t);
            }
            out[(b * NS + i) * NIB + n] = om[addr];
        }
    }
}

extern "C" void kernel_launch(void* const* d_in, const int* in_sizes, int n_in,
                              void* d_out, int out_size, void* d_ws, size_t ws_size,
                              hipStream_t stream) {
    const int*   tokens   = (const int*)d_in[0];
    const int*   sim_conn = (const int*)d_in[1];
    const float* sim_mem  = (const float*)d_in[2];
    const int*   val_conn = (const int*)d_in[3];
    const float* val_mem  = (const float*)d_in[4];
    const float* agg_mem  = (const float*)d_in[5];
    const int*   out_conn = (const int*)d_in[6];
    const float* out_mem  = (const float*)d_in[7];
    float* out = (float*)d_out;
    (void)d_ws; (void)ws_size; (void)in_sizes; (void)n_in; (void)out_size;

    ram_v2<<<NB, 1024, 0, stream>>>(tokens, sim_conn, sim_mem, val_conn,
                                    val_mem, agg_mem, out_conn, out_mem, out);
}

// Round 12
// 19.431 us; speedup vs baseline: 1.2016x; 1.2016x over previous
//
#include <hip/hip_runtime.h>
#include <stdint.h>

// Problem constants (match reference)
constexpr int NB = 256;      // batch
constexpr int NS = 64;       // sequence
constexpr int NIB = 32;      // bits per token
constexpr int NH = 4;        // heads
constexpr int SIMB = 12;     // sim address bits
constexpr int VALB = 10;     // val address bits
constexpr int OUTB = 12;     // out address bits

// ROUND-10 OPTIMUM, verbatim. Single-dispatch kernel, no packing of tables:
// sim/val/agg bits are read directly as floats (>0.5f) from L2/L1. Only
// tokens are ballot-packed in-block (2 rounds). Conn tables staged in LDS
// (scalarizes their reads — round-11 showed direct global reads regress).
// One block per batch b; 1024 threads = 16 waves; lane = j.
__global__ __launch_bounds__(1024) void ram_direct(
    const int* __restrict__ tokens,      // [B][S][IB]
    const int* __restrict__ sim_conn,    // [H][12]
    const float* __restrict__ sim_mem,   // [H][4096]
    const int* __restrict__ val_conn,    // [H][IB][10]
    const float* __restrict__ val_mem,   // [H][IB][1024]
    const float* __restrict__ agg_mem,   // [H][IB][65]
    const int* __restrict__ out_conn,    // [IB][12]
    const float* __restrict__ out_mem,   // [IB][4096]
    float* __restrict__ out)             // [B][S][IB]
{
    const int b = blockIdx.x;
    const int tid = threadIdx.x, lane = tid & 63, wave = tid >> 6;

    __shared__ uint32_t s_tok[NS];
    __shared__ int      s_sconn[NH * SIMB];       // 48
    __shared__ int      s_vconn[NH * NIB * VALB]; // 1280
    __shared__ int      s_oconn[NIB * OUTB];      // 384
    __shared__ uint32_t s_ip[NS][NH];
    __shared__ uint32_t s_jp[NS][NH];
    __shared__ uint64_t s_att[NS][NH];
    __shared__ uint64_t s_proj[NH][NIB];
    __shared__ uint32_t s_comb[NS][NH];

    // ---- stage 0: in-block token pack (ballot) + conn tables to LDS ----
    {
        const int base = b * (NS * NIB);
#pragma unroll
        for (int r = 0; r < 2; ++r) {
            const int e = r * 1024 + tid;              // covers 0..2047
            uint64_t m = __ballot(tokens[base + e] & 1);
            if (lane == 0) {
                int w = e >> 5;                        // even word index
                s_tok[w]     = (uint32_t)m;
                s_tok[w + 1] = (uint32_t)(m >> 32);
            }
        }
    }
    if (tid < NH * SIMB) s_sconn[tid] = sim_conn[tid];
    for (int i = tid; i < NH * NIB * VALB; i += 1024) s_vconn[i] = val_conn[i];
    if (tid >= 640) s_oconn[tid - 640] = out_conn[tid - 640];   // 384 exactly
    __syncthreads();

    // per-lane 38-bit val_in vector: bit c == val_in[j=lane][c]
    const uint32_t tkj = s_tok[lane];
    const uint32_t rev6 = __brev((uint32_t)lane) >> 26;
    const uint64_t V = (uint64_t)tkj | ((uint64_t)rev6 << 32);

    // ---- stage 2 (threads 0..255, t=(s,h)): split sim addr into i/j parts ----
    if (tid < 256) {
        const int s = tid >> 2, h = tid & 3;
        const uint32_t tk = s_tok[s];
        uint32_t ip = 0, jp = 0;
#pragma unroll
        for (int t = 0; t < SIMB; ++t) {
            int c = s_sconn[h * SIMB + t];
            uint32_t w = 1u << (SIMB - 1 - t);
            if (c < 32)      ip += ((tk >> c) & 1u) * w;                    // qb
            else if (c < 64) jp += ((tk >> (c - 32)) & 1u) * w;             // kb
            else if (c < 70) ip += (((uint32_t)s >> (69 - c)) & 1u) * w;    // qp
            else             jp += (((uint32_t)s >> (75 - c)) & 1u) * w;    // kp
        }
        s_ip[s][h] = ip;
        s_jp[s][h] = jp;
    }

    // ---- stage 3: proj masks via ballot. 16 waves x 8 = 128 (h,n).
    //      val bit read DIRECT as float from L2/L1 (4 KB row per round). ----
    for (int r = 0; r < 8; ++r) {
        const int hn = wave * 8 + r;
        const int* conn = s_vconn + hn * VALB;
        uint32_t addr = 0;
#pragma unroll
        for (int t = 0; t < VALB; ++t)
            addr += (uint32_t)((V >> conn[t]) & 1ull) << (VALB - 1 - t);
        uint64_t m = __ballot(val_mem[hn * 1024 + addr] > 0.5f);
        if (lane == 0) s_proj[hn >> 5][hn & 31] = m;
    }
    __syncthreads();   // covers stage 2 + stage 3 writes

    // ---- stage 4: attend masks via ballot. 16 waves x 16 = 256 (i,h).
    //      sim bit read DIRECT as float from L2/L1 (16 KB per h). ----
    for (int r = 0; r < 16; ++r) {
        const int idx = wave * 16 + r;
        const int i = idx >> 2, h = idx & 3;
        uint32_t addr = s_ip[i][h] + s_jp[lane][h];
        uint64_t m = __ballot(sim_mem[h * 4096 + addr] > 0.5f);
        if (lane == 0) s_att[i][h] = m & (~0ull >> (63 - i));   // causal
    }
    __syncthreads();

    // ---- stage 5: counts -> agg bit -> comb word. 1024 threads = (i,h,q).
    //      agg bit read DIRECT as float (33 KB table, L1-hot). ----
    {
        const int i = tid >> 4, h = (tid >> 2) & 3, q = tid & 3;
        const uint64_t am = s_att[i][h];
        uint32_t word = 0;
#pragma unroll
        for (int nn = 0; nn < 8; ++nn) {
            const int n = q * 8 + nn;
            int cnt = __popcll(am & s_proj[h][n]);     // exact integer in [0,64]
            uint32_t bit = (agg_mem[(h * NIB + n) * (NS + 1) + cnt] > 0.5f) ? 1u : 0u;
            word |= bit << n;
        }
        word = (am != 0ull) ? word : 0u;     // n_att > 0.5 gate (quad-uniform)
        word |= __shfl_xor(word, 1);
        word |= __shfl_xor(word, 2);
        if (q == 0) s_comb[i][h] = word;
    }
    __syncthreads();

    // ---- stage 6: out address gather + final float lookup. 2 outs/thread. ----
    {
        const int n = tid & 31;
        const int ii = tid >> 5;                 // 0..31
        int conn[OUTB];
#pragma unroll
        for (int t = 0; t < OUTB; ++t) conn[t] = s_oconn[n * OUTB + t];
        const float* om = out_mem + n * 4096;
#pragma unroll
        for (int k = 0; k < 2; ++k) {
            const int i = ii + k * 32;
            uint64_t lo = (uint64_t)s_comb[i][0] | ((uint64_t)s_comb[i][1] << 32);
            uint64_t hi = (uint64_t)s_comb[i][2] | ((uint64_t)s_comb[i][3] << 32);
            uint32_t addr = 0;
#pragma unroll
            for (int t = 0; t < OUTB; ++t) {
                int c = conn[t];
                uint64_t w = (c < 64) ? lo : hi;
                addr += (uint32_t)((w >> (c & 63)) & 1ull) << (OUTB - 1 - t);
            }
            out[(b * NS + i) * NIB + n] = om[addr];
        }
    }
}

extern "C" void kernel_launch(void* const* d_in, const int* in_sizes, int n_in,
                              void* d_out, int out_size, void* d_ws, size_t ws_size,
                              hipStream_t stream) {
    const int*   tokens   = (const int*)d_in[0];
    const int*   sim_conn = (const int*)d_in[1];
    const float* sim_mem  = (const float*)d_in[2];
    const int*   val_conn = (const int*)d_in[3];
    const float* val_mem  = (const float*)d_in[4];
    const float* agg_mem  = (const float*)d_in[5];
    const int*   out_conn = (const int*)d_in[6];
    const float* out_mem  = (const float*)d_in[7];
    float* out = (float*)d_out;
    (void)d_ws; (void)ws_size; (void)in_sizes; (void)n_in; (void)out_size;

    ram_direct<<<NB, 1024, 0, stream>>>(tokens, sim_conn, sim_mem, val_conn,
                                        val_mem, agg_mem, out_conn, out_mem, out);
}